// Round 4
// baseline (391.079 us; speedup 1.0000x reference)
//
#include <hip/hip_runtime.h>

// DEQ fused kernel, round 4: 32x32x16 MFMA (halved MFMA issue, +20% FLOP/cyc).
//
// out = relu^{(30)}(z Wz^T + inj) @ Wd^T + bd,  inj = x Ux^T + b
//
// Wave decomposition: 4 waves/block over a 64-row tile; wn = n-half (64 hid
// units, 2 tiles of 32), wm = m-half (32 rows = one MFMA-N tile of 32).
// D[n][m] = sum_k Wz[n][k] Z^T[k][m], Wz as A-operand (register/AGPR resident).
// 32x32x16 C/D layout: col = lane&31 = m, row = 8*(reg>>2) + 4*(lane>>5) +
// (reg&3) -> reg-quads are 4 consecutive n -> packed ds_write_b64; next
// iteration's B-frag wants 8 consecutive k at fixed m -> ds_read_b128.
// One barrier/iter, double-buffered 32 KB LDS, 16B-chunk XOR swizzle.

typedef __attribute__((ext_vector_type(8)))  __bf16 bf16x8;
typedef __attribute__((ext_vector_type(4)))  __bf16 bf16x4;
typedef __attribute__((ext_vector_type(16))) float  floatx16;

#define MFMA32(a, b, c) __builtin_amdgcn_mfma_f32_32x32x16_bf16((a), (b), (c), 0, 0, 0)

static constexpr int kBsz = 262144;
static constexpr int kTM  = 64;    // batch rows per block

__device__ __forceinline__ bf16x8 cvt_bf16x8(float4 a, float4 b) {
  bf16x8 r;
  r[0] = (__bf16)a.x; r[1] = (__bf16)a.y; r[2] = (__bf16)a.z; r[3] = (__bf16)a.w;
  r[4] = (__bf16)b.x; r[5] = (__bf16)b.y; r[6] = (__bf16)b.z; r[7] = (__bf16)b.w;
  return r;
}

// swizzled bf16-index of (row m, 16B-chunk c, bf16 offset within chunk)
__device__ __forceinline__ int zidx(int m, int c, int off) {
  return m * 128 + 8 * (c ^ (m & 7)) + off;
}

__global__ void __launch_bounds__(256) deq_fused(
    const float* __restrict__ x,    // [B,64]
    const float* __restrict__ Wz,   // [128,128]
    const float* __restrict__ Ux,   // [128,64]
    const float* __restrict__ bvec, // [128]
    const float* __restrict__ Wd,   // [64,128]
    const float* __restrict__ bd,   // [64]
    const int*  __restrict__ n_iters_p,
    float* __restrict__ out)        // [B,64]
{
  __shared__ __align__(16) __bf16 zl[2][kTM * 128];  // 32 KB double buffer

  const int tid  = threadIdx.x;
  const int lane = tid & 63;
  const int wv   = tid >> 6;   // 0..3
  const int wn   = wv & 1;     // n-half: hid units [64*wn, 64*wn+64)
  const int wm   = wv >> 1;    // m-half: rows [32*wm, 32*wm+32)
  const int l31  = lane & 31;
  const int h    = lane >> 5;  // 0..1
  const int ml   = 32 * wm + l31;          // local row (= MFMA col for this wave)
  const int grow = blockIdx.x * kTM + ml;  // global batch row
  const int iters = *n_iters_p;

  // ---- Wz half as A-fragments: A[n][k], n = 64wn + 32nt + l31, k = 16ks+8h+j
  bf16x8 awz[2][8];
#pragma unroll
  for (int nt = 0; nt < 2; ++nt) {
    const int n = 64 * wn + 32 * nt + l31;
#pragma unroll
    for (int ks = 0; ks < 8; ++ks) {
      const float4* p = (const float4*)(Wz + n * 128 + 16 * ks + 8 * h);
      awz[nt][ks] = cvt_bf16x8(p[0], p[1]);
    }
  }

  // ---- inj in 32x32 C/D layout: reg r -> n = 64wn + 32nt + 8(r>>2) + 4h + (r&3)
  floatx16 inj[2];
#pragma unroll
  for (int nt = 0; nt < 2; ++nt) {
#pragma unroll
    for (int g = 0; g < 4; ++g) {
      const float4 bv = *(const float4*)(bvec + 64 * wn + 32 * nt + 8 * g + 4 * h);
      inj[nt][4 * g + 0] = bv.x; inj[nt][4 * g + 1] = bv.y;
      inj[nt][4 * g + 2] = bv.z; inj[nt][4 * g + 3] = bv.w;
    }
  }
  {
    // encoder: inj += Ux @ x^T  (K=64 -> 4 k-steps of 16)
    bf16x8 aux[2][4];
#pragma unroll
    for (int nt = 0; nt < 2; ++nt) {
      const int n = 64 * wn + 32 * nt + l31;
#pragma unroll
      for (int ks = 0; ks < 4; ++ks) {
        const float4* p = (const float4*)(Ux + n * 64 + 16 * ks + 8 * h);
        aux[nt][ks] = cvt_bf16x8(p[0], p[1]);
      }
    }
#pragma unroll
    for (int ks = 0; ks < 4; ++ks) {
      const float4* px = (const float4*)(x + (size_t)grow * 64 + 16 * ks + 8 * h);
      const bf16x8 bx = cvt_bf16x8(px[0], px[1]);
#pragma unroll
      for (int nt = 0; nt < 2; ++nt)
        inj[nt] = MFMA32(aux[nt][ks], bx, inj[nt]);
    }
  }

  // ---- z1 = relu(inj) (z0 = 0) -> buffer 0
  // reg quad g of tile nt -> 4 consecutive n at col 64wn+32nt+8g+4h: chunk 8wn+4nt+g
#pragma unroll
  for (int nt = 0; nt < 2; ++nt) {
#pragma unroll
    for (int g = 0; g < 4; ++g) {
      bf16x4 z4;
#pragma unroll
      for (int i = 0; i < 4; ++i) z4[i] = (__bf16)fmaxf(inj[nt][4 * g + i], 0.0f);
      *(bf16x4*)&zl[0][zidx(ml, 8 * wn + 4 * nt + g, 4 * h)] = z4;
    }
  }

  // ---- fixed-point loop: 1 barrier/iter, 16 MFMA + 8 b128 reads + 8 b64 writes
  int pb = 0;
  for (int t = 0; t < iters - 1; ++t) {
    __syncthreads();
    // B-frags: B[k][m], k = 16ks + 8h + j -> chunk 2ks+h at row ml
    bf16x8 bz[8];
#pragma unroll
    for (int ks = 0; ks < 8; ++ks)
      bz[ks] = *(const bf16x8*)&zl[pb][zidx(ml, 2 * ks + h, 0)];
    const int nb = pb ^ 1;
#pragma unroll
    for (int nt = 0; nt < 2; ++nt) {
      floatx16 acc = MFMA32(awz[nt][0], bz[0], inj[nt]);  // inj folded into first C
#pragma unroll
      for (int ks = 1; ks < 8; ++ks)
        acc = MFMA32(awz[nt][ks], bz[ks], acc);
#pragma unroll
      for (int g = 0; g < 4; ++g) {
        bf16x4 z4;
#pragma unroll
        for (int i = 0; i < 4; ++i) z4[i] = (__bf16)fmaxf(acc[4 * g + i], 0.0f);
        *(bf16x4*)&zl[nb][zidx(ml, 8 * wn + 4 * nt + g, 4 * h)] = z4;
      }
    }
    pb = nb;
  }
  __syncthreads();

  // ---- decoder: D[o][m] = sum_k Wd[o][k] Z^T[k][m] + bd,  o = 32wn + ...
  {
    bf16x8 awd[8];
    const int o = 32 * wn + l31;
#pragma unroll
    for (int ks = 0; ks < 8; ++ks) {
      const float4* p = (const float4*)(Wd + o * 128 + 16 * ks + 8 * h);
      awd[ks] = cvt_bf16x8(p[0], p[1]);
    }
    floatx16 acc;
#pragma unroll
    for (int g = 0; g < 4; ++g) {
      const float4 bv = *(const float4*)(bd + 32 * wn + 8 * g + 4 * h);
      acc[4 * g + 0] = bv.x; acc[4 * g + 1] = bv.y;
      acc[4 * g + 2] = bv.z; acc[4 * g + 3] = bv.w;
    }
    bf16x8 bz[8];
#pragma unroll
    for (int ks = 0; ks < 8; ++ks)
      bz[ks] = *(const bf16x8*)&zl[pb][zidx(ml, 2 * ks + h, 0)];
#pragma unroll
    for (int ks = 0; ks < 8; ++ks)
      acc = MFMA32(awd[ks], bz[ks], acc);
    // store: reg quad g -> 4 consecutive o at 32wn + 8g + 4h, row grow
#pragma unroll
    for (int g = 0; g < 4; ++g) {
      float4 ov;
      ov.x = acc[4 * g + 0]; ov.y = acc[4 * g + 1];
      ov.z = acc[4 * g + 2]; ov.w = acc[4 * g + 3];
      *(float4*)(out + (size_t)grow * 64 + 32 * wn + 8 * g + 4 * h) = ov;
    }
  }
}

extern "C" void kernel_launch(void* const* d_in, const int* in_sizes, int n_in,
                              void* d_out, int out_size, void* d_ws, size_t ws_size,
                              hipStream_t stream) {
  const float* x  = (const float*)d_in[0];
  const float* Wz = (const float*)d_in[1];
  const float* Ux = (const float*)d_in[2];
  const float* b  = (const float*)d_in[3];
  const float* Wd = (const float*)d_in[4];
  const float* bd = (const float*)d_in[5];
  const int* n_it = (const int*)d_in[6];
  float* out = (float*)d_out;
  (void)in_sizes; (void)n_in; (void)d_ws; (void)ws_size; (void)out_size;

  dim3 grid(kBsz / kTM);  // 4096 blocks
  deq_fused<<<grid, 256, 0, stream>>>(x, Wz, Ux, b, Wd, bd, n_it, out);
}